// Round 1
// 969.441 us; speedup vs baseline: 1.8522x; 1.8522x over previous
//
#include <hip/hip_runtime.h>
#include <stdint.h>

// ---------------------------------------------------------------------------
// Net_52948356825721: 4x edge-conv GNN.
// R4: the per-edge MLP GEMMs ([128000, 644/704/128] @ [., 64] + [128000,64]@[64,64])
// ran on the fp32 VALU (MfmaUtil=0, VALUBusy 23.6%, 23 TF effective). Rewritten
// on MFMA 16x16x32 bf16 with split-fp32 (hi/lo bf16, 3 products) for accuracy:
//   a = a_hi + a_lo (truncate/RNE split); a*b ~= ah*bh + al*bh + ah*bl
// Residual ~2^-17 relative -> absmax ~1e-4 expected.
// Per block: 128 edges, 4 waves, each wave owns 32 edges x 64 cols
// (2 row-tiles x 4 col-tiles of 16x16, acc f32x4[2][4]).
// A staged in LDS in *fragment order* (lane-contiguous 16B reads, no bank
// conflicts); W pre-packed to global scratch in the SAME k-slot bijection
// k = 4q + (r&3) + 16*(r>>2)  (k-permutation cancels when shared by A and B).
// C/D mapping (HW-verified): col = lane&15, row = 4*(lane>>4) + reg.
// Second GEMM (h @ w2) via in-LDS fragment transpose of h (wave-private,
// reuses the A buffer after the last K-step barrier).
// conv1's +4 edge_rot K-tail is added on VALU in the epilogue.
// Node GEMMs / scatter-mean / heads unchanged from the 1795us version.
// ---------------------------------------------------------------------------

#define N_NODES 10000
#define N_EDGES 128000
#define E_HALF  64000

typedef unsigned short u16;
constexpr int PAD = 18;

using bf16x8 = __attribute__((ext_vector_type(8))) short;
using f32x4  = __attribute__((ext_vector_type(4))) float;

#define MFMA16(A, B, C) C = __builtin_amdgcn_mfma_f32_16x16x32_bf16(A, B, C, 0, 0, 0)

__device__ __align__(256) float g_acc[N_NODES * 64];
__device__ __align__(256) float g_deg[N_NODES];
__device__ __align__(256) float g_P[N_NODES * 128];
__device__ __align__(256) float g_x1[N_NODES * 64];
__device__ __align__(256) float g_x2[N_NODES * 64];
__device__ __align__(256) float g_x3[N_NODES * 64];
__device__ __align__(256) float g_exA[(size_t)N_EDGES * 64];
__device__ __align__(256) float g_exB[(size_t)N_EDGES * 64];
__device__ __align__(256) u16  g_wpA_hi[11 * 4096];   // W packed: [s][kt][ct][lane][r]
__device__ __align__(256) u16  g_wpA_lo[11 * 4096];
__device__ __align__(256) u16  g_wp2_hi[4096];
__device__ __align__(256) u16  g_wp2_lo[4096];
__device__ __align__(256) int g_row[N_EDGES];
__device__ __align__(256) int g_col[N_EDGES];
__device__ int g_mode;   // 0 = bf16 I/O, 1 = f32 I/O
__device__ int g_is64;   // edge_index is int64

__device__ __forceinline__ float b2f(u16 u) {
    return __uint_as_float(((unsigned int)u) << 16);
}
__device__ __forceinline__ u16 f2b(float f) {
    unsigned int u = __float_as_uint(f);
    u += 0x7FFFu + ((u >> 16) & 1u);   // RNE
    return (u16)(u >> 16);
}
__device__ __forceinline__ float ldf(const u16* p)   { return b2f(*p); }
__device__ __forceinline__ float ldf(const float* p) { return *p; }
__device__ __forceinline__ void  stf(u16* p, float v)   { *p = f2b(v); }
__device__ __forceinline__ void  stf(float* p, float v) { *p = v; }

__device__ __forceinline__ float4 load4(const float* p) { return *(const float4*)p; }
__device__ __forceinline__ float4 load4(const u16* p) {
    ushort4 v = *(const ushort4*)p;
    return make_float4(b2f(v.x), b2f(v.y), b2f(v.z), b2f(v.w));
}

// split 4 f32 into packed bf16 hi (truncation) + lo (RNE of exact residual)
__device__ __forceinline__ void split_pack(float4 v, uint2& hi, uint2& lo) {
    unsigned int ux = __float_as_uint(v.x), uy = __float_as_uint(v.y);
    unsigned int uz = __float_as_uint(v.z), uw = __float_as_uint(v.w);
    unsigned int hx = ux & 0xFFFF0000u, hy = uy & 0xFFFF0000u;
    unsigned int hz = uz & 0xFFFF0000u, hw = uw & 0xFFFF0000u;
    hi.x = (hx >> 16) | hy;
    hi.y = (hz >> 16) | hw;
    u16 lx = f2b(v.x - __uint_as_float(hx));
    u16 ly = f2b(v.y - __uint_as_float(hy));
    u16 lz = f2b(v.z - __uint_as_float(hz));
    u16 lw = f2b(v.w - __uint_as_float(hw));
    lo.x = (unsigned int)lx | ((unsigned int)ly << 16);
    lo.y = (unsigned int)lz | ((unsigned int)lw << 16);
}

// weight sub-matrix ELEMENT offsets for node GEMMs (dtype-size independent)
template<int K1, int K2> struct NGOff;
template<> struct NGOff<256, 4> { static constexpr size_t hi = (size_t)260 * 64; };
template<> struct NGOff<64, 0>  { static constexpr size_t hi = (size_t)64 * 64; };
template<> struct NGOff<64, 64> { static constexpr size_t hi = (size_t)128 * 64; };

// stage one row (D elems) into k-major LDS tile: sm[(koff+k)*PAD + e]
template<int D>
__device__ __forceinline__ void stage_row(const u16* src, float* sm, int koff, int e, int t) {
    static_assert(D % 4 == 0, "D%4");
    for (int k = t * 4; k < D; k += 1024) {
        ushort4 v = *(const ushort4*)(src + k);
        sm[(koff + k + 0) * PAD + e] = b2f(v.x);
        sm[(koff + k + 1) * PAD + e] = b2f(v.y);
        sm[(koff + k + 2) * PAD + e] = b2f(v.z);
        sm[(koff + k + 3) * PAD + e] = b2f(v.w);
    }
}
template<int D>
__device__ __forceinline__ void stage_row(const float* src, float* sm, int koff, int e, int t) {
    static_assert(D % 4 == 0, "D%4");
    for (int k = t * 4; k < D; k += 1024) {
        float4 v = *(const float4*)(src + k);
        sm[(koff + k + 0) * PAD + e] = v.x;
        sm[(koff + k + 1) * PAD + e] = v.y;
        sm[(koff + k + 2) * PAD + e] = v.z;
        sm[(koff + k + 3) * PAD + e] = v.w;
    }
}

// --- dtype + index-width detection (1 block, 64 threads) --------------------
__global__ void detect_kernel(const void* x_org_v, const int* __restrict__ eidx) {
    const u16* w = (const u16*)x_org_v;
    const int t = threadIdx.x;
    int ok = 0;
    for (int i = t; i < 128; i += 64) {
        u16 v = w[i];
        int ex = (v >> 7) & 0xFF;
        ok += ((ex >= 0x68 && ex <= 0x88) || ((v & 0x7FFFu) == 0)) ? 1 : 0;
    }
    #pragma unroll
    for (int off = 32; off >= 1; off >>= 1) ok += __shfl_xor(ok, off);
    bool allz = true;
    for (int i = t; i < 2048; i += 64) allz = allz && (eidx[2 * i + 1] == 0);
    unsigned long long m = __ballot(allz);
    if (t == 0) {
        g_mode = (ok >= 110) ? 0 : 1;
        g_is64 = (m == ~0ull) ? 1 : 0;
    }
}

__global__ void cvt_idx(const int* __restrict__ eidx) {
    const int e = blockIdx.x * 256 + threadIdx.x;   // exact: 500*256
    if (g_is64) {
        g_row[e] = eidx[2 * e];
        g_col[e] = eidx[2 * (e + N_EDGES)];
    } else {
        g_row[e] = eidx[e];
        g_col[e] = eidx[e + N_EDGES];
    }
}

__global__ void zero_all() {
    const int i = blockIdx.x * 256 + threadIdx.x;   // 2500 blocks -> 640000
    g_acc[i] = 0.f;
    if (i < N_NODES) g_deg[i] = 0.f;
}

__global__ void deg_kernel() {
    const int e = blockIdx.x * 256 + threadIdx.x;
    if (e < N_EDGES) atomicAdd(&g_deg[g_row[e]], 1.0f);
}

// --- P[n,0:64] = [A1|A2] @ W[0:K] ; P[n,64:128] = [A1|A2] @ W[hi:hi+K] ------
template<int K1, typename TA1, int K2, typename TA2, typename TW>
__device__ void node_gemm_body(float* sm, const TA1* A1, const TA2* A2,
                               const TW* Wbase, float* P) {
    constexpr int K = K1 + K2;
    const TW* Blo = Wbase;
    const TW* Bhi = Wbase + NGOff<K1, K2>::hi;
    const int t = threadIdx.x;
    const int c = t & 127;
    const int g = t >> 7;
    const int r0 = blockIdx.x * 16;
    for (int e = 0; e < 16; ++e) {
        stage_row<K1>(A1 + (size_t)(r0 + e) * K1, sm, 0, e, t);
        if constexpr (K2 > 0)
            stage_row<K2>(A2 + (size_t)(r0 + e) * K2, sm, K1, e, t);
    }
    __syncthreads();
    float acc[16];
    #pragma unroll
    for (int e = 0; e < 16; ++e) acc[e] = 0.f;
    const TW* Bp = (c < 64) ? (Blo + c) : (Bhi + (c - 64));
    const int kb = g * (K / 2), ke = kb + K / 2;
    for (int k = kb; k < ke; ++k) {
        float w = ldf(Bp + (size_t)k * 64);
        #pragma unroll
        for (int e = 0; e < 16; ++e) acc[e] += sm[k * PAD + e] * w;
    }
    __syncthreads();                               // reuse sm: red[2][16][128]
    #pragma unroll
    for (int e = 0; e < 16; ++e) sm[(g * 16 + e) * 128 + c] = acc[e];
    __syncthreads();
    #pragma unroll
    for (int j = 0; j < 8; ++j) {
        int e = g * 8 + j;
        P[(size_t)(r0 + e) * 128 + c] = sm[e * 128 + c] + sm[(16 + e) * 128 + c];
    }
}

template<int K1, int K2>
__global__ void __launch_bounds__(256) node_gemm_in(
        const void* A1, const void* A2, const void* W, float* __restrict__ P) {
    extern __shared__ float sm[];
    if (g_mode == 0)
        node_gemm_body<K1, u16, K2, u16, u16>(sm, (const u16*)A1, (const u16*)A2,
                                              (const u16*)W, P);
    else
        node_gemm_body<K1, float, K2, float, float>(sm, (const float*)A1,
                                              (const float*)A2, (const float*)W, P);
}

template<int K1, int K2>
__global__ void __launch_bounds__(256) node_gemm_ws(
        const float* A1, const float* A2, const void* W, float* __restrict__ P) {
    extern __shared__ float sm[];
    if (g_mode == 0)
        node_gemm_body<K1, float, K2, float, u16>(sm, A1, A2, (const u16*)W, P);
    else
        node_gemm_body<K1, float, K2, float, float>(sm, A1, A2, (const float*)W, P);
}

// --- weight pre-pack: frag order [s][kt][ct][lane][r], hi/lo split ----------
template<typename TW>
__device__ void pack_w_body(const TW* w1, const TW* w2, int we, int ns) {
    const int idx = blockIdx.x * 256 + threadIdx.x;
    const int t1 = ns * 4096;
    if (idx < t1) {
        const int s = idx >> 12;
        const int rem = idx & 4095;
        const int kt = rem >> 11, ct = (rem >> 9) & 3, l = (rem >> 3) & 63, r = rem & 7;
        const int k = s * 64 + kt * 32 + 4 * (l >> 4) + (r & 3) + 16 * (r >> 2);
        const float v = ldf(w1 + (size_t)(we + k) * 64 + ct * 16 + (l & 15));
        const u16 hh = f2b(v);
        g_wpA_hi[idx] = hh;
        g_wpA_lo[idx] = f2b(v - b2f(hh));
    } else if (idx < t1 + 4096) {
        const int rem = idx - t1;
        const int kt = rem >> 11, ct = (rem >> 9) & 3, l = (rem >> 3) & 63, r = rem & 7;
        const int k = kt * 32 + 4 * (l >> 4) + (r & 3) + 16 * (r >> 2);
        const float v = ldf(w2 + (size_t)k * 64 + ct * 16 + (l & 15));
        const u16 hh = f2b(v);
        g_wp2_hi[rem] = hh;
        g_wp2_lo[rem] = f2b(v - b2f(hh));
    }
}
__global__ void pack_w_k(const void* w1, const void* w2, int we, int ns) {
    if (g_mode == 0) pack_w_body<u16>((const u16*)w1, (const u16*)w2, we, ns);
    else             pack_w_body<float>((const float*)w1, (const float*)w2, we, ns);
}

// --- MFMA edge conv ---------------------------------------------------------
// block = 128 edges, 256 threads (4 waves). Wave w owns edges [w*32, w*32+32).
// LDS A tile (per 64-k step): hi plane smA[0:8192], lo plane smA[8192:16384],
// element (kt, rt16, lane, r) at ((kt*8 + rt16)*64 + lane)*8 + r.
// After the K loop, the same buffer holds the h fragments per wave:
//   wave base w*4096; hi [0:2048), lo [2048:4096);
//   element (kt2, rt, lane, r) at ((kt2*2 + rt)*64 + lane)*8 + r.
template<typename TA, typename TW, int NSA, int DB, bool RELU_OUT>
__device__ __forceinline__ void edge_mfma_body(
        u16* smA, int* srow, int* scol, float* b1s, float* b2s,
        float* rot, float* wtl,
        const TA* efa, const float* efb, const TA* rotsrc,
        const TW* w1, const TW* b1v, const TW* b2v, float* eout, int we) {
    constexpr int NS_TOT = NSA + (DB == 64 ? 1 : 0);
    const int t = threadIdx.x;
    const int lane = t & 63, wid = t >> 6;
    const int q = lane >> 4, n = lane & 15;
    const int e0 = blockIdx.x * 128;

    if (t < 128) srow[t] = g_row[e0 + t];
    else         scol[t - 128] = g_col[e0 + t - 128];
    if (t >= 128 && t < 192) b1s[t - 128] = ldf(b1v + (t - 128));
    if (t >= 192)            b2s[t - 192] = ldf(b2v + (t - 192));
    if constexpr (DB == 4) {
        if (t < 128) {
            float4 r4 = load4(rotsrc + (size_t)(e0 + t) * 4);
            rot[t * 4 + 0] = r4.x; rot[t * 4 + 1] = r4.y;
            rot[t * 4 + 2] = r4.z; rot[t * 4 + 3] = r4.w;
        }
        wtl[t] = ldf(w1 + (size_t)(we + NSA * 64 + (t >> 6)) * 64 + (t & 63));
    }

    f32x4 acc[2][4];
    #pragma unroll
    for (int a_ = 0; a_ < 2; ++a_)
        #pragma unroll
        for (int b_ = 0; b_ < 4; ++b_)
            acc[a_][b_] = (f32x4){0.f, 0.f, 0.f, 0.f};

    const int eb = t >> 4;     // 0..15: edge sub-row
    const int cc = t & 15;     // float4 chunk within 64-k step

    for (int s = 0; s < NS_TOT; ++s) {
        // ---- stage 128x64 f32 -> hi/lo bf16 in frag order
        #pragma unroll
        for (int p = 0; p < 8; ++p) {
            const int e = p * 16 + eb;
            float4 v;
            if (s < NSA) v = load4(efa + (size_t)(e0 + e) * (NSA * 64) + s * 64 + cc * 4);
            else         v = load4(efb + (size_t)(e0 + e) * 64 + cc * 4);
            uint2 hi, lo; split_pack(v, hi, lo);
            const int elem = (((cc >> 3) * 8 + (e >> 4)) * 64 + (cc & 3) * 16 + (e & 15)) * 8
                           + ((cc >> 2) & 1) * 4;
            *(uint2*)&smA[elem]        = hi;
            *(uint2*)&smA[elem + 8192] = lo;
        }
        __syncthreads();
        // ---- 2x kt of {4 A-frags, 4 ct x (2 B-frags, 6 MFMA)}
        const u16* wph = g_wpA_hi + s * 4096;
        const u16* wpl = g_wpA_lo + s * 4096;
        #pragma unroll
        for (int kt = 0; kt < 2; ++kt) {
            const int r0 = ((kt * 8 + wid * 2 + 0) * 64 + lane) * 8;
            const int r1 = ((kt * 8 + wid * 2 + 1) * 64 + lane) * 8;
            bf16x8 ah0 = *(const bf16x8*)&smA[r0];
            bf16x8 ah1 = *(const bf16x8*)&smA[r1];
            bf16x8 al0 = *(const bf16x8*)&smA[r0 + 8192];
            bf16x8 al1 = *(const bf16x8*)&smA[r1 + 8192];
            #pragma unroll
            for (int ct = 0; ct < 4; ++ct) {
                bf16x8 bh = *(const bf16x8*)&wph[(kt * 4 + ct) * 512 + lane * 8];
                bf16x8 bl = *(const bf16x8*)&wpl[(kt * 4 + ct) * 512 + lane * 8];
                MFMA16(ah0, bh, acc[0][ct]);
                MFMA16(ah1, bh, acc[1][ct]);
                MFMA16(al0, bh, acc[0][ct]);
                MFMA16(al1, bh, acc[1][ct]);
                MFMA16(ah0, bl, acc[0][ct]);
                MFMA16(ah1, bl, acc[1][ct]);
            }
        }
        __syncthreads();
    }

    // ---- epilogue: h = relu(acc + b1 + P_r + P_c [+ rot tail]) -> frag LDS
    #pragma unroll
    for (int rt = 0; rt < 2; ++rt) {
        #pragma unroll
        for (int ct = 0; ct < 4; ++ct) {
            #pragma unroll
            for (int i = 0; i < 4; ++i) {
                const int rl = wid * 32 + rt * 16 + 4 * q + i;
                const int col = ct * 16 + n;
                float v = acc[rt][ct][i] + b1s[col]
                        + g_P[(size_t)srow[rl] * 128 + col]
                        + g_P[(size_t)scol[rl] * 128 + 64 + col];
                if constexpr (DB == 4) {
                    v += rot[rl * 4 + 0] * wtl[0 * 64 + col]
                       + rot[rl * 4 + 1] * wtl[1 * 64 + col]
                       + rot[rl * 4 + 2] * wtl[2 * 64 + col]
                       + rot[rl * 4 + 3] * wtl[3 * 64 + col];
                }
                v = fmaxf(v, 0.f);
                unsigned int hb = __float_as_uint(v) & 0xFFFF0000u;
                const u16 hh = (u16)(hb >> 16);
                const u16 hl = f2b(v - __uint_as_float(hb));
                const int off = wid * 4096
                              + (((ct >> 1) * 2 + rt) * 64 + (n >> 2) * 16 + 4 * q + i) * 8
                              + (ct & 1) * 4 + (n & 3);
                smA[off]        = hh;
                smA[off + 2048] = hl;
            }
        }
    }
    // wave-private region: in-wave ds ordering handled by compiler waits

    // ---- second GEMM: o = h @ w2 + b2
    f32x4 oacc[2][4];
    #pragma unroll
    for (int rt = 0; rt < 2; ++rt)
        #pragma unroll
        for (int ct = 0; ct < 4; ++ct) {
            const float bb = b2s[ct * 16 + n];
            oacc[rt][ct] = (f32x4){bb, bb, bb, bb};
        }
    #pragma unroll
    for (int kt = 0; kt < 2; ++kt) {
        const int r0 = wid * 4096 + ((kt * 2 + 0) * 64 + lane) * 8;
        const int r1 = wid * 4096 + ((kt * 2 + 1) * 64 + lane) * 8;
        bf16x8 ah0 = *(const bf16x8*)&smA[r0];
        bf16x8 ah1 = *(const bf16x8*)&smA[r1];
        bf16x8 al0 = *(const bf16x8*)&smA[r0 + 2048];
        bf16x8 al1 = *(const bf16x8*)&smA[r1 + 2048];
        #pragma unroll
        for (int ct = 0; ct < 4; ++ct) {
            bf16x8 bh = *(const bf16x8*)&g_wp2_hi[(kt * 4 + ct) * 512 + lane * 8];
            bf16x8 bl = *(const bf16x8*)&g_wp2_lo[(kt * 4 + ct) * 512 + lane * 8];
            MFMA16(ah0, bh, oacc[0][ct]);
            MFMA16(ah1, bh, oacc[1][ct]);
            MFMA16(al0, bh, oacc[0][ct]);
            MFMA16(al1, bh, oacc[1][ct]);
            MFMA16(ah0, bl, oacc[0][ct]);
            MFMA16(ah1, bl, oacc[1][ct]);
        }
    }

    // ---- scatter (pre-relu) + edge output
    #pragma unroll
    for (int rt = 0; rt < 2; ++rt) {
        #pragma unroll
        for (int ct = 0; ct < 4; ++ct) {
            #pragma unroll
            for (int i = 0; i < 4; ++i) {
                const int rl = wid * 32 + rt * 16 + 4 * q + i;
                const int col = ct * 16 + n;
                const float v = oacc[rt][ct][i];
                atomicAdd(&g_acc[(size_t)srow[rl] * 64 + col], v);
                eout[(size_t)(e0 + rl) * 64 + col] = RELU_OUT ? fmaxf(v, 0.f) : v;
            }
        }
    }
}

template<int NSA, int DB, bool RELU_OUT>
__global__ void __launch_bounds__(256, 4) edge_mfma_in(
        const void* efa, const float* efb, const void* rotsrc,
        const void* w1, const void* b1, const void* b2, float* eout, int we) {
    __shared__ u16 smA[16384];
    __shared__ int srow[128], scol[128];
    __shared__ float b1s[64], b2s[64], rot[512], wtl[256];
    if (g_mode == 0)
        edge_mfma_body<u16, u16, NSA, DB, RELU_OUT>(smA, srow, scol, b1s, b2s, rot, wtl,
            (const u16*)efa, efb, (const u16*)rotsrc,
            (const u16*)w1, (const u16*)b1, (const u16*)b2, eout, we);
    else
        edge_mfma_body<float, float, NSA, DB, RELU_OUT>(smA, srow, scol, b1s, b2s, rot, wtl,
            (const float*)efa, efb, (const float*)rotsrc,
            (const float*)w1, (const float*)b1, (const float*)b2, eout, we);
}

template<int NSA, int DB, bool RELU_OUT>
__global__ void __launch_bounds__(256, 4) edge_mfma_ws(
        const float* efa, const float* efb,
        const void* w1, const void* b1, const void* b2, float* eout, int we) {
    __shared__ u16 smA[16384];
    __shared__ int srow[128], scol[128];
    __shared__ float b1s[64], b2s[64], rot[512], wtl[256];
    if (g_mode == 0)
        edge_mfma_body<float, u16, NSA, DB, RELU_OUT>(smA, srow, scol, b1s, b2s, rot, wtl,
            efa, efb, (const float*)nullptr,
            (const u16*)w1, (const u16*)b1, (const u16*)b2, eout, we);
    else
        edge_mfma_body<float, float, NSA, DB, RELU_OUT>(smA, srow, scol, b1s, b2s, rot, wtl,
            efa, efb, (const float*)nullptr,
            (const float*)w1, (const float*)b1, (const float*)b2, eout, we);
}

// --- x_i = (acc/max(deg,1)) [relu?] -> f32 [N,64]; re-zeroes acc ------------
template<bool RELU>
__global__ void finalize_k(float* __restrict__ dst) {
    const int idx = blockIdx.x * 256 + threadIdx.x;  // exact grid
    float v = g_acc[idx] / fmaxf(g_deg[idx >> 6], 1.0f);
    g_acc[idx] = 0.f;
    if (RELU) v = fmaxf(v, 0.f);
    dst[idx] = v;
}

// --- x4=relu(mean) -> lin1 [64->4] -> L2 normalize -> out -------------------
template<typename T>
__device__ void final_node_body(const T* w, const T* b, T* out) {
    const int t = threadIdx.x;
    const int lane = t & 63;
    const int n = blockIdx.x * 4 + (t >> 6);
    float inv = 1.0f / fmaxf(g_deg[n], 1.0f);
    float x4 = fmaxf(g_acc[(size_t)n * 64 + lane] * inv, 0.0f);
    float r[4];
    #pragma unroll
    for (int j = 0; j < 4; ++j) {
        float v = x4 * ldf(w + lane * 4 + j);
        #pragma unroll
        for (int off = 32; off >= 1; off >>= 1) v += __shfl_xor(v, off);
        r[j] = v + ldf(b + j);
    }
    float nrm = sqrtf(r[0]*r[0] + r[1]*r[1] + r[2]*r[2] + r[3]*r[3]);
    float dn = fmaxf(nrm, 1e-12f);
    if (lane < 4) stf(out + n * 4 + lane, r[lane] / dn);
}
__global__ void final_node(const void* w, const void* b, void* out) {
    if (g_mode == 0) final_node_body<u16>((const u16*)w, (const u16*)b, (u16*)out);
    else             final_node_body<float>((const float*)w, (const float*)b, (float*)out);
}

// --- pred_edge_res: h=ex4[:H]+ex4[H:]; relu(h@w1+b1)@w2+b2 ------------------
template<typename T>
__device__ void edge_head_body(const float* ex4, const T* w1, const T* b1,
                               const T* w2, const T* b2, T* out) {
    __shared__ float lw1[2048];
    __shared__ float lw2[32];
    const int t = threadIdx.x;
    for (int i = t; i < 2048; i += 256) lw1[i] = ldf(w1 + i);
    if (t < 32) lw2[t] = ldf(w2 + t);
    __syncthreads();
    const int e = blockIdx.x * 256 + t;           // exact: 250*256 = 64000
    float a[32];
    #pragma unroll
    for (int j = 0; j < 32; ++j) a[j] = ldf(b1 + j);
    const float* p0 = ex4 + (size_t)e * 64;
    const float* p1 = ex4 + (size_t)(e + E_HALF) * 64;
    for (int c = 0; c < 64; ++c) {
        float h = p0[c] + p1[c];
        #pragma unroll
        for (int j = 0; j < 32; ++j) a[j] += h * lw1[c * 32 + j];
    }
    float s = ldf(b2);
    #pragma unroll
    for (int j = 0; j < 32; ++j) s += fmaxf(a[j], 0.f) * lw2[j];
    stf(out + e, s);
}
__global__ void __launch_bounds__(256) edge_head(const float* ex4,
        const void* w1, const void* b1, const void* w2, const void* b2,
        void* out) {
    if (g_mode == 0)
        edge_head_body<u16>(ex4, (const u16*)w1, (const u16*)b1,
                            (const u16*)w2, (const u16*)b2, (u16*)out + 40000);
    else
        edge_head_body<float>(ex4, (const float*)w1, (const float*)b1,
                              (const float*)w2, (const float*)b2, (float*)out + 40000);
}

// --- layout tripwire: fill out with ~996.5 pattern --------------------------
__global__ void sentinel_fill(unsigned int* out, int n_words) {
    int i = blockIdx.x * 256 + threadIdx.x;
    if (i < n_words) out[i] = 0x44794479u;
}

static void* sym_addr(const void* symbol) {
    void* p = nullptr;
    (void)hipGetSymbolAddress(&p, symbol);
    return p;
}

extern "C" void kernel_launch(void* const* d_in, const int* in_sizes, int n_in,
                              void* d_out, int out_size, void* d_ws, size_t ws_size,
                              hipStream_t stream) {
    (void)d_ws; (void)ws_size;
    bool ok = (n_in == 27) && (out_size == 104000)
           && (in_sizes[0] == 2560000) && (in_sizes[2] == 256000)
           && (in_sizes[3] == 81920000) && (in_sizes[5] == 74496)
           && (in_sizes[21] == 256) && (in_sizes[25] == 32);
    if (!ok) {   // wrong layout assumption -> recognizable absmax ~996
        sentinel_fill<<<204, 256, 0, stream>>>((unsigned int*)d_out, 52000);
        return;
    }
    const void* x_org     = d_in[0];
    const void* x_rot     = d_in[1];
    const int*  eidx      = (const int*)d_in[2];
    const void* edge_attr = d_in[3];
    const void* edge_rot  = d_in[4];

    float* P   = (float*)sym_addr(HIP_SYMBOL(g_P));
    float* x1  = (float*)sym_addr(HIP_SYMBOL(g_x1));
    float* x2  = (float*)sym_addr(HIP_SYMBOL(g_x2));
    float* x3  = (float*)sym_addr(HIP_SYMBOL(g_x3));
    float* exA = (float*)sym_addr(HIP_SYMBOL(g_exA));
    float* exB = (float*)sym_addr(HIP_SYMBOL(g_exB));

    detect_kernel<<<1, 64, 0, stream>>>(x_org, eidx);
    cvt_idx<<<500, 256, 0, stream>>>(eidx);
    zero_all<<<2500, 256, 0, stream>>>();
    deg_kernel<<<500, 256, 0, stream>>>();

    // conv1: c1_w1 rows [0,260)=W_r, [260,520)=W_c, [520,1160)=W_attr, [1160,1164)=W_rot
    node_gemm_in<256, 4><<<625, 256, 18720, stream>>>(x_org, x_rot, d_in[5], P);
    pack_w_k<<<176, 256, 0, stream>>>(d_in[5], d_in[7], 520, 10);
    edge_mfma_in<10, 4, true><<<1000, 256, 0, stream>>>(
        edge_attr, nullptr, edge_rot, d_in[5], d_in[6], d_in[8], exA, 520);   // ex1
    finalize_k<false><<<2500, 256, 0, stream>>>(x1);

    // conv2: rows [0,64)=W_r, [64,128)=W_c, [128,832)=W_e on [edge_attr|ex1]
    node_gemm_ws<64, 0><<<625, 256, 16384, stream>>>(x1, (const float*)nullptr,
                                                     d_in[9], P);
    pack_w_k<<<192, 256, 0, stream>>>(d_in[9], d_in[11], 128, 11);
    edge_mfma_in<10, 64, true><<<1000, 256, 0, stream>>>(
        edge_attr, exA, nullptr, d_in[9], d_in[10], d_in[12], exB, 128);      // ex2
    finalize_k<true><<<2500, 256, 0, stream>>>(x2);

    // conv3: rows [0,128)=W_r on [x2|x1], [128,256)=W_c, [256,384)=W_e on [ex2|ex1]
    node_gemm_ws<64, 64><<<625, 256, 16384, stream>>>(x2, x1, d_in[13], P);
    pack_w_k<<<48, 256, 0, stream>>>(d_in[13], d_in[15], 256, 2);
    edge_mfma_ws<1, 64, true><<<1000, 256, 0, stream>>>(
        exB, exA, d_in[13], d_in[14], d_in[16], exA, 256);                    // ex3 over ex1
    finalize_k<true><<<2500, 256, 0, stream>>>(x3);

    // conv4: [x3|x2] nodes, [ex3|ex2] edges
    node_gemm_ws<64, 64><<<625, 256, 16384, stream>>>(x3, x2, d_in[17], P);
    pack_w_k<<<48, 256, 0, stream>>>(d_in[17], d_in[19], 256, 2);
    edge_mfma_ws<1, 64, false><<<1000, 256, 0, stream>>>(
        exA, exB, d_in[17], d_in[18], d_in[20], exB, 256);                    // ex4 over ex2

    final_node<<<2500, 256, 0, stream>>>(d_in[21], d_in[22], d_out);
    edge_head<<<250, 256, 0, stream>>>(exB, d_in[23], d_in[24], d_in[25], d_in[26],
                                       d_out);
}

// Round 2
// 922.843 us; speedup vs baseline: 1.9457x; 1.0505x over previous
//
#include <hip/hip_runtime.h>
#include <stdint.h>

// ---------------------------------------------------------------------------
// Net_52948356825721: 4x edge-conv GNN.
// R4: edge MLPs on MFMA split-bf16 (hi/lo, 3 products) -> 1795 -> 969 us.
// R5: (a) node GEMMs P = A @ [W_r|W_c] moved from fp32 VALU to the same
//     split-bf16 MFMA path (conv1 K=256 MFMA + 4-wide x_rot VALU tail);
//     (b) XOR bank-swizzle on the frag-order LDS staging (store AND read):
//     blk ^= ((blk>>4)&3) ^ (kt<<2) folds q/kt into the bank bits -- the
//     linear layout put row (constant per staging subgroup) in the bank
//     field -> 8-deep writes; swizzle restores the 4-cycle BW floor.
// k-slot bijection k = 4q + (r&3) + 16(r>>2) shared by A-staging and the
// W pre-pack (permutation cancels). C/D: col = lane&15, row = 4*(lane>>4)+reg.
// ---------------------------------------------------------------------------

#define N_NODES 10000
#define N_EDGES 128000
#define E_HALF  64000

typedef unsigned short u16;

using bf16x8 = __attribute__((ext_vector_type(8))) short;
using f32x4  = __attribute__((ext_vector_type(4))) float;

#define MFMA16(A, B, C) C = __builtin_amdgcn_mfma_f32_16x16x32_bf16(A, B, C, 0, 0, 0)

__device__ __align__(256) float g_acc[N_NODES * 64];
__device__ __align__(256) float g_deg[N_NODES];
__device__ __align__(256) float g_P[N_NODES * 128];
__device__ __align__(256) float g_x1[N_NODES * 64];
__device__ __align__(256) float g_x2[N_NODES * 64];
__device__ __align__(256) float g_x3[N_NODES * 64];
__device__ __align__(256) float g_exA[(size_t)N_EDGES * 64];
__device__ __align__(256) float g_exB[(size_t)N_EDGES * 64];
__device__ __align__(256) u16  g_wpA_hi[11 * 4096];   // edge W1 pack [s][kt][ct4][l][r]
__device__ __align__(256) u16  g_wpA_lo[11 * 4096];
__device__ __align__(256) u16  g_wp2_hi[4096];        // edge W2 pack
__device__ __align__(256) u16  g_wp2_lo[4096];
__device__ __align__(256) u16  g_wnp_hi[4 * 8192];    // node W pack [s][kt][ct8][l][r]
__device__ __align__(256) u16  g_wnp_lo[4 * 8192];
__device__ __align__(256) int g_row[N_EDGES];
__device__ __align__(256) int g_col[N_EDGES];
__device__ int g_mode;   // 0 = bf16 I/O, 1 = f32 I/O
__device__ int g_is64;   // edge_index is int64

__device__ __forceinline__ float b2f(u16 u) {
    return __uint_as_float(((unsigned int)u) << 16);
}
__device__ __forceinline__ u16 f2b(float f) {
    unsigned int u = __float_as_uint(f);
    u += 0x7FFFu + ((u >> 16) & 1u);   // RNE
    return (u16)(u >> 16);
}
__device__ __forceinline__ float ldf(const u16* p)   { return b2f(*p); }
__device__ __forceinline__ float ldf(const float* p) { return *p; }
__device__ __forceinline__ void  stf(u16* p, float v)   { *p = f2b(v); }
__device__ __forceinline__ void  stf(float* p, float v) { *p = v; }

__device__ __forceinline__ float4 load4(const float* p) { return *(const float4*)p; }
__device__ __forceinline__ float4 load4(const u16* p) {
    ushort4 v = *(const ushort4*)p;
    return make_float4(b2f(v.x), b2f(v.y), b2f(v.z), b2f(v.w));
}

// bank swizzle on 16B-block index: fold q (bits 4-5) and kt (bit KTB) into
// the low-3 (bank) bits. Applied identically on staging store and frag read.
template<int KTB>
__device__ __forceinline__ int swz(int b) {
    return b ^ ((b >> 4) & 3) ^ (((b >> KTB) & 1) << 2);
}

// split 4 f32 into packed bf16 hi (truncation) + lo (RNE of exact residual)
__device__ __forceinline__ void split_pack(float4 v, uint2& hi, uint2& lo) {
    unsigned int ux = __float_as_uint(v.x), uy = __float_as_uint(v.y);
    unsigned int uz = __float_as_uint(v.z), uw = __float_as_uint(v.w);
    unsigned int hx = ux & 0xFFFF0000u, hy = uy & 0xFFFF0000u;
    unsigned int hz = uz & 0xFFFF0000u, hw = uw & 0xFFFF0000u;
    hi.x = (hx >> 16) | hy;
    hi.y = (hz >> 16) | hw;
    u16 lx = f2b(v.x - __uint_as_float(hx));
    u16 ly = f2b(v.y - __uint_as_float(hy));
    u16 lz = f2b(v.z - __uint_as_float(hz));
    u16 lw = f2b(v.w - __uint_as_float(hw));
    lo.x = (unsigned int)lx | ((unsigned int)ly << 16);
    lo.y = (unsigned int)lz | ((unsigned int)lw << 16);
}

// --- dtype + index-width detection (1 block, 64 threads) --------------------
__global__ void detect_kernel(const void* x_org_v, const int* __restrict__ eidx) {
    const u16* w = (const u16*)x_org_v;
    const int t = threadIdx.x;
    int ok = 0;
    for (int i = t; i < 128; i += 64) {
        u16 v = w[i];
        int ex = (v >> 7) & 0xFF;
        ok += ((ex >= 0x68 && ex <= 0x88) || ((v & 0x7FFFu) == 0)) ? 1 : 0;
    }
    #pragma unroll
    for (int off = 32; off >= 1; off >>= 1) ok += __shfl_xor(ok, off);
    bool allz = true;
    for (int i = t; i < 2048; i += 64) allz = allz && (eidx[2 * i + 1] == 0);
    unsigned long long m = __ballot(allz);
    if (t == 0) {
        g_mode = (ok >= 110) ? 0 : 1;
        g_is64 = (m == ~0ull) ? 1 : 0;
    }
}

__global__ void cvt_idx(const int* __restrict__ eidx) {
    const int e = blockIdx.x * 256 + threadIdx.x;   // exact: 500*256
    if (g_is64) {
        g_row[e] = eidx[2 * e];
        g_col[e] = eidx[2 * (e + N_EDGES)];
    } else {
        g_row[e] = eidx[e];
        g_col[e] = eidx[e + N_EDGES];
    }
}

__global__ void zero_all() {
    const int i = blockIdx.x * 256 + threadIdx.x;   // 2500 blocks -> 640000
    g_acc[i] = 0.f;
    if (i < N_NODES) g_deg[i] = 0.f;
}

__global__ void deg_kernel() {
    const int e = blockIdx.x * 256 + threadIdx.x;
    if (e < N_EDGES) atomicAdd(&g_deg[g_row[e]], 1.0f);
}

// --- weight pre-pack: edge W1 (4-ct), W2, node W (8-ct), hi/lo split --------
template<typename TW>
__device__ void pack_w_body(const TW* w1, const TW* w2, int we, int ns,
                            int hioff, int nsn) {
    const int idx = blockIdx.x * 256 + threadIdx.x;
    const int t1 = ns * 4096;
    if (idx < t1) {
        const int s = idx >> 12;
        const int rem = idx & 4095;
        const int kt = rem >> 11, ct = (rem >> 9) & 3, l = (rem >> 3) & 63, r = rem & 7;
        const int k = s * 64 + kt * 32 + 4 * (l >> 4) + (r & 3) + 16 * (r >> 2);
        const float v = ldf(w1 + (size_t)(we + k) * 64 + ct * 16 + (l & 15));
        const u16 hh = f2b(v);
        g_wpA_hi[idx] = hh;
        g_wpA_lo[idx] = f2b(v - b2f(hh));
    } else if (idx < t1 + 4096) {
        const int rem = idx - t1;
        const int kt = rem >> 11, ct = (rem >> 9) & 3, l = (rem >> 3) & 63, r = rem & 7;
        const int k = kt * 32 + 4 * (l >> 4) + (r & 3) + 16 * (r >> 2);
        const float v = ldf(w2 + (size_t)k * 64 + ct * 16 + (l & 15));
        const u16 hh = f2b(v);
        g_wp2_hi[rem] = hh;
        g_wp2_lo[rem] = f2b(v - b2f(hh));
    } else if (idx < t1 + 4096 + nsn * 8192) {
        const int rem = idx - t1 - 4096;
        const int s = rem >> 13;
        const int kt = (rem >> 12) & 1, ct = (rem >> 9) & 7, l = (rem >> 3) & 63, r = rem & 7;
        const int k = s * 64 + kt * 32 + 4 * (l >> 4) + (r & 3) + 16 * (r >> 2);
        const int col = ct * 16 + (l & 15);
        const int row = (col < 64) ? k : (hioff + k);
        const float v = ldf(w1 + (size_t)row * 64 + (col & 63));
        const u16 hh = f2b(v);
        g_wnp_hi[rem] = hh;
        g_wnp_lo[rem] = f2b(v - b2f(hh));
    }
}
__global__ void pack_w_k(const void* w1, const void* w2, int we, int ns,
                         int hioff, int nsn) {
    if (g_mode == 0) pack_w_body<u16>((const u16*)w1, (const u16*)w2, we, ns, hioff, nsn);
    else             pack_w_body<float>((const float*)w1, (const float*)w2, we, ns, hioff, nsn);
}

// --- node MFMA GEMM: P[10000,128] = A[10000,K] @ [W_r|W_c] ------------------
// block = 64 rows, 4 waves; wave w: rows [w*16,(w+1)*16) x 128 cols (8 ct).
// NS1 steps from A1 (stride NS1*64), NS2 from A2. TAIL: +x_rot[4] @ w1 rows
// {256..259 | 516..519} on VALU in the epilogue (conv1 K=260).
template<typename TA, int NS1, int NS2, bool TAIL>
__device__ void node_mfma_body(u16* smA, float* smrot, float* smwt,
        const TA* A1, const float* A2, const TA* rotsrc, const TA* w1, float* P) {
    constexpr int NS = NS1 + NS2;
    const int t = threadIdx.x;
    const int lane = t & 63, wid = t >> 6;
    const int q = lane >> 4, n = lane & 15;
    const int r0b = blockIdx.x * 64;

    if constexpr (TAIL) {
        if (t < 64) {
            const int rr = min(r0b + t, N_NODES - 1);
            float4 v = load4(rotsrc + (size_t)rr * 4);
            smrot[t * 4 + 0] = v.x; smrot[t * 4 + 1] = v.y;
            smrot[t * 4 + 2] = v.z; smrot[t * 4 + 3] = v.w;
        }
        for (int i = t; i < 512; i += 256) {
            const int j = i >> 7, c = i & 127;
            const int row = (c < 64) ? (256 + j) : (516 + j);
            smwt[i] = ldf(w1 + (size_t)row * 64 + (c & 63));
        }
    }

    f32x4 acc[8];
    #pragma unroll
    for (int ct = 0; ct < 8; ++ct) acc[ct] = (f32x4){0.f, 0.f, 0.f, 0.f};

    const int eb = t >> 4;     // 0..15
    const int cc = t & 15;

    for (int s = 0; s < NS; ++s) {
        #pragma unroll
        for (int p = 0; p < 4; ++p) {
            const int e = p * 16 + eb;
            const int row = min(r0b + e, N_NODES - 1);
            float4 v;
            if constexpr (NS2 > 0)
                v = (s < NS1) ? load4(A1 + (size_t)row * (NS1 * 64) + s * 64 + cc * 4)
                              : load4(A2 + (size_t)row * (NS2 * 64) + (s - NS1) * 64 + cc * 4);
            else
                v = load4(A1 + (size_t)row * (NS1 * 64) + s * 64 + cc * 4);
            uint2 hi, lo; split_pack(v, hi, lo);
            const int blk = ((cc >> 3) * 4 + (e >> 4)) * 64 + (cc & 3) * 16 + (e & 15);
            const int elem = swz<8>(blk) * 8 + ((cc >> 2) & 1) * 4;
            *(uint2*)&smA[elem]        = hi;
            *(uint2*)&smA[elem + 4096] = lo;
        }
        __syncthreads();
        const u16* wph = g_wnp_hi + s * 8192;
        const u16* wpl = g_wnp_lo + s * 8192;
        #pragma unroll
        for (int kt = 0; kt < 2; ++kt) {
            const int ad = swz<8>((kt * 4 + wid) * 64 + lane) * 8;
            bf16x8 ah = *(const bf16x8*)&smA[ad];
            bf16x8 al = *(const bf16x8*)&smA[ad + 4096];
            #pragma unroll
            for (int ct = 0; ct < 8; ++ct) {
                bf16x8 bh = *(const bf16x8*)&wph[(kt * 8 + ct) * 512 + lane * 8];
                bf16x8 bl = *(const bf16x8*)&wpl[(kt * 8 + ct) * 512 + lane * 8];
                MFMA16(ah, bh, acc[ct]);
                MFMA16(al, bh, acc[ct]);
                MFMA16(ah, bl, acc[ct]);
            }
        }
        __syncthreads();
    }

    #pragma unroll
    for (int ct = 0; ct < 8; ++ct) {
        #pragma unroll
        for (int i = 0; i < 4; ++i) {
            const int rl = wid * 16 + 4 * q + i;
            const int row = r0b + rl;
            const int col = ct * 16 + n;
            float v = acc[ct][i];
            if constexpr (TAIL)
                v += smrot[rl * 4 + 0] * smwt[0 * 128 + col]
                   + smrot[rl * 4 + 1] * smwt[1 * 128 + col]
                   + smrot[rl * 4 + 2] * smwt[2 * 128 + col]
                   + smrot[rl * 4 + 3] * smwt[3 * 128 + col];
            if (row < N_NODES) P[(size_t)row * 128 + col] = v;
        }
    }
}

template<int NS1, bool TAIL>
__global__ void __launch_bounds__(256) node_mfma_in(
        const void* A1, const void* rotsrc, const void* w1, float* __restrict__ P) {
    __shared__ u16 smA[8192];
    __shared__ float smrot[256], smwt[512];
    if (g_mode == 0)
        node_mfma_body<u16, NS1, 0, TAIL>(smA, smrot, smwt, (const u16*)A1,
            nullptr, (const u16*)rotsrc, (const u16*)w1, P);
    else
        node_mfma_body<float, NS1, 0, TAIL>(smA, smrot, smwt, (const float*)A1,
            nullptr, (const float*)rotsrc, (const float*)w1, P);
}

template<int NS1, int NS2>
__global__ void __launch_bounds__(256) node_mfma_ws(
        const float* A1, const float* A2, float* __restrict__ P) {
    __shared__ u16 smA[8192];
    __shared__ float smrot[256], smwt[512];
    node_mfma_body<float, NS1, NS2, false>(smA, smrot, smwt, A1, A2,
        (const float*)nullptr, (const float*)nullptr, P);
}

// --- MFMA edge conv ---------------------------------------------------------
// block = 128 edges, 256 threads (4 waves). Wave w owns edges [w*32, w*32+32).
// LDS A tile per 64-k step, frag order + swz<9> bank swizzle:
// hi plane smA[0:8192], lo plane smA[8192:16384].
// After the K loop, smA holds per-wave h fragments (linear, wave-private).
template<typename TA, typename TW, int NSA, int DB, bool RELU_OUT>
__device__ __forceinline__ void edge_mfma_body(
        u16* smA, int* srow, int* scol, float* b1s, float* b2s,
        float* rot, float* wtl,
        const TA* efa, const float* efb, const TA* rotsrc,
        const TW* w1, const TW* b1v, const TW* b2v, float* eout, int we) {
    constexpr int NS_TOT = NSA + (DB == 64 ? 1 : 0);
    const int t = threadIdx.x;
    const int lane = t & 63, wid = t >> 6;
    const int q = lane >> 4, n = lane & 15;
    const int e0 = blockIdx.x * 128;

    if (t < 128) srow[t] = g_row[e0 + t];
    else         scol[t - 128] = g_col[e0 + t - 128];
    if (t >= 128 && t < 192) b1s[t - 128] = ldf(b1v + (t - 128));
    if (t >= 192)            b2s[t - 192] = ldf(b2v + (t - 192));
    if constexpr (DB == 4) {
        if (t < 128) {
            float4 r4 = load4(rotsrc + (size_t)(e0 + t) * 4);
            rot[t * 4 + 0] = r4.x; rot[t * 4 + 1] = r4.y;
            rot[t * 4 + 2] = r4.z; rot[t * 4 + 3] = r4.w;
        }
        wtl[t] = ldf(w1 + (size_t)(we + NSA * 64 + (t >> 6)) * 64 + (t & 63));
    }

    f32x4 acc[2][4];
    #pragma unroll
    for (int a_ = 0; a_ < 2; ++a_)
        #pragma unroll
        for (int b_ = 0; b_ < 4; ++b_)
            acc[a_][b_] = (f32x4){0.f, 0.f, 0.f, 0.f};

    const int eb = t >> 4;     // 0..15: edge sub-row
    const int cc = t & 15;     // float4 chunk within 64-k step

    for (int s = 0; s < NS_TOT; ++s) {
        // ---- stage 128x64 f32 -> hi/lo bf16 in swizzled frag order
        #pragma unroll
        for (int p = 0; p < 8; ++p) {
            const int e = p * 16 + eb;
            float4 v;
            if (s < NSA) v = load4(efa + (size_t)(e0 + e) * (NSA * 64) + s * 64 + cc * 4);
            else         v = load4(efb + (size_t)(e0 + e) * 64 + cc * 4);
            uint2 hi, lo; split_pack(v, hi, lo);
            const int blk = ((cc >> 3) * 8 + (e >> 4)) * 64 + (cc & 3) * 16 + (e & 15);
            const int elem = swz<9>(blk) * 8 + ((cc >> 2) & 1) * 4;
            *(uint2*)&smA[elem]        = hi;
            *(uint2*)&smA[elem + 8192] = lo;
        }
        __syncthreads();
        // ---- 2x kt of {4 A-frags, 4 ct x (2 B-frags, 6 MFMA)}
        const u16* wph = g_wpA_hi + s * 4096;
        const u16* wpl = g_wpA_lo + s * 4096;
        #pragma unroll
        for (int kt = 0; kt < 2; ++kt) {
            const int b0 = (kt * 8 + wid * 2 + 0) * 64 + lane;
            const int b1 = (kt * 8 + wid * 2 + 1) * 64 + lane;
            const int r0 = swz<9>(b0) * 8;
            const int r1 = swz<9>(b1) * 8;
            bf16x8 ah0 = *(const bf16x8*)&smA[r0];
            bf16x8 ah1 = *(const bf16x8*)&smA[r1];
            bf16x8 al0 = *(const bf16x8*)&smA[r0 + 8192];
            bf16x8 al1 = *(const bf16x8*)&smA[r1 + 8192];
            #pragma unroll
            for (int ct = 0; ct < 4; ++ct) {
                bf16x8 bh = *(const bf16x8*)&wph[(kt * 4 + ct) * 512 + lane * 8];
                bf16x8 bl = *(const bf16x8*)&wpl[(kt * 4 + ct) * 512 + lane * 8];
                MFMA16(ah0, bh, acc[0][ct]);
                MFMA16(ah1, bh, acc[1][ct]);
                MFMA16(al0, bh, acc[0][ct]);
                MFMA16(al1, bh, acc[1][ct]);
                MFMA16(ah0, bl, acc[0][ct]);
                MFMA16(ah1, bl, acc[1][ct]);
            }
        }
        __syncthreads();
    }

    // ---- epilogue: h = relu(acc + b1 + P_r + P_c [+ rot tail]) -> frag LDS
    #pragma unroll
    for (int rt = 0; rt < 2; ++rt) {
        #pragma unroll
        for (int ct = 0; ct < 4; ++ct) {
            #pragma unroll
            for (int i = 0; i < 4; ++i) {
                const int rl = wid * 32 + rt * 16 + 4 * q + i;
                const int col = ct * 16 + n;
                float v = acc[rt][ct][i] + b1s[col]
                        + g_P[(size_t)srow[rl] * 128 + col]
                        + g_P[(size_t)scol[rl] * 128 + 64 + col];
                if constexpr (DB == 4) {
                    v += rot[rl * 4 + 0] * wtl[0 * 64 + col]
                       + rot[rl * 4 + 1] * wtl[1 * 64 + col]
                       + rot[rl * 4 + 2] * wtl[2 * 64 + col]
                       + rot[rl * 4 + 3] * wtl[3 * 64 + col];
                }
                v = fmaxf(v, 0.f);
                unsigned int hb = __float_as_uint(v) & 0xFFFF0000u;
                const u16 hh = (u16)(hb >> 16);
                const u16 hl = f2b(v - __uint_as_float(hb));
                const int off = wid * 4096
                              + (((ct >> 1) * 2 + rt) * 64 + (n >> 2) * 16 + 4 * q + i) * 8
                              + (ct & 1) * 4 + (n & 3);
                smA[off]        = hh;
                smA[off + 2048] = hl;
            }
        }
    }
    // wave-private region: in-wave ds ordering handled by compiler waits

    // ---- second GEMM: o = h @ w2 + b2
    f32x4 oacc[2][4];
    #pragma unroll
    for (int rt = 0; rt < 2; ++rt)
        #pragma unroll
        for (int ct = 0; ct < 4; ++ct) {
            const float bb = b2s[ct * 16 + n];
            oacc[rt][ct] = (f32x4){bb, bb, bb, bb};
        }
    #pragma unroll
    for (int kt = 0; kt < 2; ++kt) {
        const int r0 = wid * 4096 + ((kt * 2 + 0) * 64 + lane) * 8;
        const int r1 = wid * 4096 + ((kt * 2 + 1) * 64 + lane) * 8;
        bf16x8 ah0 = *(const bf16x8*)&smA[r0];
        bf16x8 ah1 = *(const bf16x8*)&smA[r1];
        bf16x8 al0 = *(const bf16x8*)&smA[r0 + 2048];
        bf16x8 al1 = *(const bf16x8*)&smA[r1 + 2048];
        #pragma unroll
        for (int ct = 0; ct < 4; ++ct) {
            bf16x8 bh = *(const bf16x8*)&g_wp2_hi[(kt * 4 + ct) * 512 + lane * 8];
            bf16x8 bl = *(const bf16x8*)&g_wp2_lo[(kt * 4 + ct) * 512 + lane * 8];
            MFMA16(ah0, bh, oacc[0][ct]);
            MFMA16(ah1, bh, oacc[1][ct]);
            MFMA16(al0, bh, oacc[0][ct]);
            MFMA16(al1, bh, oacc[1][ct]);
            MFMA16(ah0, bl, oacc[0][ct]);
            MFMA16(ah1, bl, oacc[1][ct]);
        }
    }

    // ---- scatter (pre-relu) + edge output
    #pragma unroll
    for (int rt = 0; rt < 2; ++rt) {
        #pragma unroll
        for (int ct = 0; ct < 4; ++ct) {
            #pragma unroll
            for (int i = 0; i < 4; ++i) {
                const int rl = wid * 32 + rt * 16 + 4 * q + i;
                const int col = ct * 16 + n;
                const float v = oacc[rt][ct][i];
                atomicAdd(&g_acc[(size_t)srow[rl] * 64 + col], v);
                eout[(size_t)(e0 + rl) * 64 + col] = RELU_OUT ? fmaxf(v, 0.f) : v;
            }
        }
    }
}

template<int NSA, int DB, bool RELU_OUT>
__global__ void __launch_bounds__(256, 4) edge_mfma_in(
        const void* efa, const float* efb, const void* rotsrc,
        const void* w1, const void* b1, const void* b2, float* eout, int we) {
    __shared__ u16 smA[16384];
    __shared__ int srow[128], scol[128];
    __shared__ float b1s[64], b2s[64], rot[512], wtl[256];
    if (g_mode == 0)
        edge_mfma_body<u16, u16, NSA, DB, RELU_OUT>(smA, srow, scol, b1s, b2s, rot, wtl,
            (const u16*)efa, efb, (const u16*)rotsrc,
            (const u16*)w1, (const u16*)b1, (const u16*)b2, eout, we);
    else
        edge_mfma_body<float, float, NSA, DB, RELU_OUT>(smA, srow, scol, b1s, b2s, rot, wtl,
            (const float*)efa, efb, (const float*)rotsrc,
            (const float*)w1, (const float*)b1, (const float*)b2, eout, we);
}

template<int NSA, int DB, bool RELU_OUT>
__global__ void __launch_bounds__(256, 4) edge_mfma_ws(
        const float* efa, const float* efb,
        const void* w1, const void* b1, const void* b2, float* eout, int we) {
    __shared__ u16 smA[16384];
    __shared__ int srow[128], scol[128];
    __shared__ float b1s[64], b2s[64], rot[512], wtl[256];
    if (g_mode == 0)
        edge_mfma_body<float, u16, NSA, DB, RELU_OUT>(smA, srow, scol, b1s, b2s, rot, wtl,
            efa, efb, (const float*)nullptr,
            (const u16*)w1, (const u16*)b1, (const u16*)b2, eout, we);
    else
        edge_mfma_body<float, float, NSA, DB, RELU_OUT>(smA, srow, scol, b1s, b2s, rot, wtl,
            efa, efb, (const float*)nullptr,
            (const float*)w1, (const float*)b1, (const float*)b2, eout, we);
}

// --- x_i = (acc/max(deg,1)) [relu?] -> f32 [N,64]; re-zeroes acc ------------
template<bool RELU>
__global__ void finalize_k(float* __restrict__ dst) {
    const int idx = blockIdx.x * 256 + threadIdx.x;  // exact grid
    float v = g_acc[idx] / fmaxf(g_deg[idx >> 6], 1.0f);
    g_acc[idx] = 0.f;
    if (RELU) v = fmaxf(v, 0.f);
    dst[idx] = v;
}

// --- x4=relu(mean) -> lin1 [64->4] -> L2 normalize -> out -------------------
template<typename T>
__device__ void final_node_body(const T* w, const T* b, T* out) {
    const int t = threadIdx.x;
    const int lane = t & 63;
    const int n = blockIdx.x * 4 + (t >> 6);
    float inv = 1.0f / fmaxf(g_deg[n], 1.0f);
    float x4 = fmaxf(g_acc[(size_t)n * 64 + lane] * inv, 0.0f);
    float r[4];
    #pragma unroll
    for (int j = 0; j < 4; ++j) {
        float v = x4 * ldf(w + lane * 4 + j);
        #pragma unroll
        for (int off = 32; off >= 1; off >>= 1) v += __shfl_xor(v, off);
        r[j] = v + ldf(b + j);
    }
    float nrm = sqrtf(r[0]*r[0] + r[1]*r[1] + r[2]*r[2] + r[3]*r[3]);
    float dn = fmaxf(nrm, 1e-12f);
    if (lane < 4) stf(out + n * 4 + lane, r[lane] / dn);
}
__global__ void final_node(const void* w, const void* b, void* out) {
    if (g_mode == 0) final_node_body<u16>((const u16*)w, (const u16*)b, (u16*)out);
    else             final_node_body<float>((const float*)w, (const float*)b, (float*)out);
}

// --- pred_edge_res: h=ex4[:H]+ex4[H:]; relu(h@w1+b1)@w2+b2 ------------------
template<typename T>
__device__ void edge_head_body(const float* ex4, const T* w1, const T* b1,
                               const T* w2, const T* b2, T* out) {
    __shared__ float lw1[2048];
    __shared__ float lw2[32];
    const int t = threadIdx.x;
    for (int i = t; i < 2048; i += 256) lw1[i] = ldf(w1 + i);
    if (t < 32) lw2[t] = ldf(w2 + t);
    __syncthreads();
    const int e = blockIdx.x * 256 + t;           // exact: 250*256 = 64000
    float a[32];
    #pragma unroll
    for (int j = 0; j < 32; ++j) a[j] = ldf(b1 + j);
    const float* p0 = ex4 + (size_t)e * 64;
    const float* p1 = ex4 + (size_t)(e + E_HALF) * 64;
    for (int c = 0; c < 64; ++c) {
        float h = p0[c] + p1[c];
        #pragma unroll
        for (int j = 0; j < 32; ++j) a[j] += h * lw1[c * 32 + j];
    }
    float s = ldf(b2);
    #pragma unroll
    for (int j = 0; j < 32; ++j) s += fmaxf(a[j], 0.f) * lw2[j];
    stf(out + e, s);
}
__global__ void __launch_bounds__(256) edge_head(const float* ex4,
        const void* w1, const void* b1, const void* w2, const void* b2,
        void* out) {
    if (g_mode == 0)
        edge_head_body<u16>(ex4, (const u16*)w1, (const u16*)b1,
                            (const u16*)w2, (const u16*)b2, (u16*)out + 40000);
    else
        edge_head_body<float>(ex4, (const float*)w1, (const float*)b1,
                              (const float*)w2, (const float*)b2, (float*)out + 40000);
}

// --- layout tripwire: fill out with ~996.5 pattern --------------------------
__global__ void sentinel_fill(unsigned int* out, int n_words) {
    int i = blockIdx.x * 256 + threadIdx.x;
    if (i < n_words) out[i] = 0x44794479u;
}

static void* sym_addr(const void* symbol) {
    void* p = nullptr;
    (void)hipGetSymbolAddress(&p, symbol);
    return p;
}

extern "C" void kernel_launch(void* const* d_in, const int* in_sizes, int n_in,
                              void* d_out, int out_size, void* d_ws, size_t ws_size,
                              hipStream_t stream) {
    (void)d_ws; (void)ws_size;
    bool ok = (n_in == 27) && (out_size == 104000)
           && (in_sizes[0] == 2560000) && (in_sizes[2] == 256000)
           && (in_sizes[3] == 81920000) && (in_sizes[5] == 74496)
           && (in_sizes[21] == 256) && (in_sizes[25] == 32);
    if (!ok) {   // wrong layout assumption -> recognizable absmax ~996
        sentinel_fill<<<204, 256, 0, stream>>>((unsigned int*)d_out, 52000);
        return;
    }
    const void* x_org     = d_in[0];
    const void* x_rot     = d_in[1];
    const int*  eidx      = (const int*)d_in[2];
    const void* edge_attr = d_in[3];
    const void* edge_rot  = d_in[4];

    float* P   = (float*)sym_addr(HIP_SYMBOL(g_P));
    float* x1  = (float*)sym_addr(HIP_SYMBOL(g_x1));
    float* x2  = (float*)sym_addr(HIP_SYMBOL(g_x2));
    float* x3  = (float*)sym_addr(HIP_SYMBOL(g_x3));
    float* exA = (float*)sym_addr(HIP_SYMBOL(g_exA));
    float* exB = (float*)sym_addr(HIP_SYMBOL(g_exB));

    detect_kernel<<<1, 64, 0, stream>>>(x_org, eidx);
    cvt_idx<<<500, 256, 0, stream>>>(eidx);
    zero_all<<<2500, 256, 0, stream>>>();
    deg_kernel<<<500, 256, 0, stream>>>();

    // conv1: c1_w1 rows [0,260)=W_r, [260,520)=W_c, [520,1160)=W_attr, [1160,1164)=W_rot
    pack_w_k<<<304, 256, 0, stream>>>(d_in[5], d_in[7], 520, 10, 260, 4);
    node_mfma_in<4, true><<<157, 256, 0, stream>>>(x_org, x_rot, d_in[5], P);
    edge_mfma_in<10, 4, true><<<1000, 256, 0, stream>>>(
        edge_attr, nullptr, edge_rot, d_in[5], d_in[6], d_in[8], exA, 520);   // ex1
    finalize_k<false><<<2500, 256, 0, stream>>>(x1);

    // conv2: rows [0,64)=W_r, [64,128)=W_c, [128,832)=W_e on [edge_attr|ex1]
    pack_w_k<<<224, 256, 0, stream>>>(d_in[9], d_in[11], 128, 11, 64, 1);
    node_mfma_ws<1, 0><<<157, 256, 0, stream>>>(x1, nullptr, P);
    edge_mfma_in<10, 64, true><<<1000, 256, 0, stream>>>(
        edge_attr, exA, nullptr, d_in[9], d_in[10], d_in[12], exB, 128);      // ex2
    finalize_k<true><<<2500, 256, 0, stream>>>(x2);

    // conv3: rows [0,128)=W_r on [x2|x1], [128,256)=W_c, [256,384)=W_e on [ex2|ex1]
    pack_w_k<<<112, 256, 0, stream>>>(d_in[13], d_in[15], 256, 2, 128, 2);
    node_mfma_ws<1, 1><<<157, 256, 0, stream>>>(x2, x1, P);
    edge_mfma_ws<1, 64, true><<<1000, 256, 0, stream>>>(
        exB, exA, d_in[13], d_in[14], d_in[16], exA, 256);                    // ex3 over ex1
    finalize_k<true><<<2500, 256, 0, stream>>>(x3);

    // conv4: [x3|x2] nodes, [ex3|ex2] edges
    pack_w_k<<<112, 256, 0, stream>>>(d_in[17], d_in[19], 256, 2, 128, 2);
    node_mfma_ws<1, 1><<<157, 256, 0, stream>>>(x3, x2, P);
    edge_mfma_ws<1, 64, false><<<1000, 256, 0, stream>>>(
        exA, exB, d_in[17], d_in[18], d_in[20], exB, 256);                    // ex4 over ex2

    final_node<<<2500, 256, 0, stream>>>(d_in[21], d_in[22], d_out);
    edge_head<<<250, 256, 0, stream>>>(exB, d_in[23], d_in[24], d_in[25], d_in[26],
                                       d_out);
}